// Round 5
// baseline (346.308 us; speedup 1.0000x reference)
//
#include <hip/hip_runtime.h>

#define B_ 4
#define NH_ 32
#define SQ_ 512
#define HD_ 128
#define MLEN_ 3584
#define KT_ 4096           // MLEN_ + SQ_
#define QB_ 128
#define KB_ 64
#define NTILE_ 64          // KT_ / KB_
#define MEMTILES_ 56       // MLEN_ / KB_

typedef float f32x4 __attribute__((ext_vector_type(4)));
typedef short s16x8 __attribute__((ext_vector_type(8)));

__device__ __forceinline__ f32x4 MFMA16(s16x8 a, s16x8 b, f32x4 c) {
    return __builtin_amdgcn_mfma_f32_16x16x32_bf16(a, b, c, 0, 0, 0);
}

__device__ __forceinline__ s16x8 cvt8(float4 a, float4 b) {
    union { s16x8 v; __bf16 h[8]; } u;
    u.h[0] = (__bf16)a.x; u.h[1] = (__bf16)a.y;
    u.h[2] = (__bf16)a.z; u.h[3] = (__bf16)a.w;
    u.h[4] = (__bf16)b.x; u.h[5] = (__bf16)b.y;
    u.h[6] = (__bf16)b.z; u.h[7] = (__bf16)b.w;
    return u.v;
}

// 8 waves x 16 q-rows, 48KB LDS, <=128 VGPR -> 2 blocks/CU, 4 waves/SIMD.
// (R4 had 4 waves x 32 rows: only 2 waves/SIMD -> latency-bound.)
__launch_bounds__(512, 4)
__global__ void attn_kernel(const float* __restrict__ q, const float* __restrict__ k,
                            const float* __restrict__ v, const float* __restrict__ mask,
                            const float* __restrict__ mem, float* __restrict__ ctx)
{
    __shared__ __bf16 Klds[KB_ * HD_];        // 16 KB, swizzled rows
    __shared__ __bf16 Vt[HD_ * KB_];          // 16 KB, transposed + swizzled
    __shared__ __bf16 Plds[8 * 16 * KB_];     // 16 KB, per-wave P [16][64]

    const int tid  = threadIdx.x;
    const int lane = tid & 63;
    const int w    = tid >> 6;                // 0..7
    const int l15  = lane & 15;
    const int l4   = lane >> 4;
    const int xv   = (lane & 7) << 4;

    // grid = 512: qt in 0..3; same head's q-tiles are bid%128-equal -> same XCD
    const int qt   = blockIdx.x >> 7;
    const int pair = blockIdx.x & 127;
    const int b    = pair >> 5;
    const int h    = pair & 31;
    const int q0   = qt * QB_;

    // ---- Q fragments (scale folded in); wave w owns rows q0 + w*16 .. +15 ----
    const float scale = 0.088388347648318447f;   // 1/sqrt(128)
    s16x8 qf[4];
    {
        const float* qbase = q + (((size_t)(b * NH_ + h)) * SQ_ + q0 + w * 16 + l15) * HD_;
        #pragma unroll
        for (int kc = 0; kc < 4; ++kc) {
            const float* p = qbase + kc * 32 + l4 * 8;
            float4 a = *(const float4*)p;
            float4 c = *(const float4*)(p + 4);
            a.x *= scale; a.y *= scale; a.z *= scale; a.w *= scale;
            c.x *= scale; c.y *= scale; c.z *= scale; c.w *= scale;
            qf[kc] = cvt8(a, c);
        }
    }

    f32x4 acc[8];
    #pragma unroll
    for (int n = 0; n < 8; ++n) acc[n] = (f32x4){0.f, 0.f, 0.f, 0.f};

    float mrun[4], lrun[4];
    #pragma unroll
    for (int i = 0; i < 4; ++i) { mrun[i] = -3.0e38f; lrun[i] = 0.f; }

    const float* maskbase = mask + ((size_t)b * SQ_ + q0 + w * 16 + l4 * 4) * KT_;

    for (int t = 0; t < NTILE_; ++t) {
        const int kv0 = t * KB_;
        const float *srcK, *srcV;
        int rstride;
        if (t < MEMTILES_) {
            const float* mrow = mem + ((size_t)b * MLEN_ + kv0) * (2 * NH_ * HD_) + h * HD_;
            srcK = mrow;
            srcV = mrow + NH_ * HD_;
            rstride = 2 * NH_ * HD_;
        } else {
            size_t off = (((size_t)b * NH_ + h) * SQ_ + (kv0 - MLEN_)) * HD_;
            srcK = k + off;
            srcV = v + off;
            rstride = HD_;
        }

        __syncthreads();   // previous tile's LDS reads complete

        // ---- K stage: 1024 x 16B chunks over 512 threads ----
        #pragma unroll
        for (int it = 0; it < 2; ++it) {
            int idx = tid + it * 512;
            int row = idx >> 4, cg = idx & 15;
            const float* p = srcK + (size_t)row * rstride + cg * 8;
            float4 a = *(const float4*)p;
            float4 c = *(const float4*)(p + 4);
            s16x8 vv = cvt8(a, c);
            int byte = row * 256 + ((cg * 16) ^ ((row & 7) << 4));
            *(s16x8*)((char*)Klds + byte) = vv;
        }
        // ---- V stage (transposed) ----
        #pragma unroll
        for (int it = 0; it < 2; ++it) {
            int idx = tid + it * 512;
            int hd = idx & 127, kvb = idx >> 7;
            const float* p = srcV + (size_t)(kvb * 8) * rstride + hd;
            union { s16x8 v; __bf16 hh[8]; } u;
            #pragma unroll
            for (int j = 0; j < 8; ++j) u.hh[j] = (__bf16)p[(size_t)j * rstride];
            int byte = hd * 128 + ((kvb * 16) ^ ((hd & 7) << 4));
            *(s16x8*)((char*)Vt + byte) = u.v;
        }

        // ---- mask loads for this tile (drain at the same barrier as the stage) ----
        float mpre[4][4];
        #pragma unroll
        for (int i = 0; i < 4; ++i) {
            const float* mp = maskbase + (size_t)i * KT_ + kv0 + l15;
            #pragma unroll
            for (int n = 0; n < 4; ++n) mpre[i][n] = mp[n * 16];
        }

        __syncthreads();   // tile staged

        // ---- S = (Q*scale) @ K^T ----
        f32x4 sa[4];
        #pragma unroll
        for (int n = 0; n < 4; ++n) sa[n] = (f32x4){0.f, 0.f, 0.f, 0.f};
        #pragma unroll
        for (int n = 0; n < 4; ++n) {
            #pragma unroll
            for (int kc = 0; kc < 4; ++kc) {
                s16x8 kf = *(const s16x8*)((const char*)Klds +
                            (n * 16 + l15) * 256 + (((kc * 4 + l4) * 16) ^ xv));
                sa[n] = MFMA16(qf[kc], kf, sa[n]);
            }
        }

        // ---- mask + online softmax (rows: l4*4 + i; cols: n*16 + l15) ----
        #pragma unroll
        for (int i = 0; i < 4; ++i) {
            sa[0][i] = fmaf(mpre[i][0], sa[0][i] + 10000.f, -10000.f);
            sa[1][i] = fmaf(mpre[i][1], sa[1][i] + 10000.f, -10000.f);
            sa[2][i] = fmaf(mpre[i][2], sa[2][i] + 10000.f, -10000.f);
            sa[3][i] = fmaf(mpre[i][3], sa[3][i] + 10000.f, -10000.f);

            float rm = fmaxf(fmaxf(sa[0][i], sa[1][i]), fmaxf(sa[2][i], sa[3][i]));
            rm = fmaxf(rm, __shfl_xor(rm, 1));
            rm = fmaxf(rm, __shfl_xor(rm, 2));
            rm = fmaxf(rm, __shfl_xor(rm, 4));
            rm = fmaxf(rm, __shfl_xor(rm, 8));

            float om = mrun[i];
            float nm = fmaxf(om, rm);
            float al = __expf(om - nm);
            mrun[i] = nm;

            float rs = 0.f;
            #pragma unroll
            for (int n = 0; n < 4; ++n) {
                float pe = __expf(sa[n][i] - nm);
                sa[n][i] = pe;
                rs += pe;
            }
            rs += __shfl_xor(rs, 1);
            rs += __shfl_xor(rs, 2);
            rs += __shfl_xor(rs, 4);
            rs += __shfl_xor(rs, 8);
            lrun[i] = lrun[i] * al + rs;

            #pragma unroll
            for (int nn = 0; nn < 8; ++nn) acc[nn][i] *= al;
        }

        // ---- P -> bf16 -> per-wave LDS [16][64] (swizzled) ----
        __bf16* pw = &Plds[w * (16 * KB_)];
        #pragma unroll
        for (int n = 0; n < 4; ++n)
            #pragma unroll
            for (int i = 0; i < 4; ++i) {
                int row = l4 * 4 + i;
                int col = n * 16 + l15;
                int byte = row * 128 + ((col * 2) ^ ((row & 7) << 4));
                *(__bf16*)((char*)pw + byte) = (__bf16)sa[n][i];
            }

        // ---- O += P @ V ----
        s16x8 pf[2];
        #pragma unroll
        for (int kt = 0; kt < 2; ++kt)
            pf[kt] = *(const s16x8*)((const char*)pw +
                          l15 * 128 + ((kt * 64 + l4 * 16) ^ xv));
        #pragma unroll
        for (int nn = 0; nn < 8; ++nn) {
            s16x8 vf0 = *(const s16x8*)((const char*)Vt +
                          (nn * 16 + l15) * 128 + ((l4 * 16) ^ xv));
            s16x8 vf1 = *(const s16x8*)((const char*)Vt +
                          (nn * 16 + l15) * 128 + ((64 + l4 * 16) ^ xv));
            acc[nn] = MFMA16(pf[0], vf0, acc[nn]);
            acc[nn] = MFMA16(pf[1], vf1, acc[nn]);
        }
    }

    // ---- epilogue: normalize + store f32 ----
    float* obase = ctx + (((size_t)(b * NH_ + h)) * SQ_ + q0 + w * 16 + l4 * 4) * HD_ + l15;
    #pragma unroll
    for (int i = 0; i < 4; ++i) {
        float inv = 1.f / lrun[i];
        #pragma unroll
        for (int nn = 0; nn < 8; ++nn)
            obase[(size_t)i * HD_ + nn * 16] = acc[nn][i] * inv;
    }
}

// cache_kv: out[b][s][part][h][d] = (part ? v : k)[b][h][s][d]
__global__ void cachekv_kernel(const float* __restrict__ k, const float* __restrict__ v,
                               float* __restrict__ out)
{
    size_t i = ((size_t)blockIdx.x * 256 + threadIdx.x) * 4;
    unsigned f = (unsigned)i;
    unsigned d    = f & 127;
    unsigned hh   = (f >> 7) & 31;
    unsigned part = (f >> 12) & 1;
    unsigned s    = (f >> 13) & 511;
    unsigned bb   = f >> 22;
    const float* src = (part ? v : k) + (((size_t)(bb * 32u + hh)) * 512u + s) * 128u + d;
    *(float4*)(out + i) = *(const float4*)src;
}

extern "C" void kernel_launch(void* const* d_in, const int* in_sizes, int n_in,
                              void* d_out, int out_size, void* d_ws, size_t ws_size,
                              hipStream_t stream) {
    const float* q    = (const float*)d_in[0];
    const float* k    = (const float*)d_in[1];
    const float* v    = (const float*)d_in[2];
    const float* mask = (const float*)d_in[3];
    const float* mem  = (const float*)d_in[4];
    float* out = (float*)d_out;

    attn_kernel<<<dim3(B_ * NH_ * (SQ_ / QB_)), dim3(512), 0, stream>>>(q, k, v, mask, mem, out);

    const int ctx_elems = B_ * NH_ * SQ_ * HD_;                 // 8388608
    const int ckv_elems = B_ * SQ_ * 2 * NH_ * HD_;             // 16777216
    cachekv_kernel<<<dim3(ckv_elems / 4 / 256), dim3(256), 0, stream>>>(k, v, out + ctx_elems);
    (void)in_sizes; (void)n_in; (void)out_size; (void)d_ws; (void)ws_size;
}

// Round 6
// 322.104 us; speedup vs baseline: 1.0751x; 1.0751x over previous
//
#include <hip/hip_runtime.h>

#define B_ 4
#define NH_ 32
#define SQ_ 512
#define HD_ 128
#define MLEN_ 3584
#define KT_ 4096           // MLEN_ + SQ_
#define QB_ 128
#define KB_ 64
#define NTILE_ 64          // KT_ / KB_
#define MEMTILES_ 56       // MLEN_ / KB_

typedef float f32x4 __attribute__((ext_vector_type(4)));
typedef short s16x8 __attribute__((ext_vector_type(8)));

__device__ __forceinline__ f32x4 MFMA16(s16x8 a, s16x8 b, f32x4 c) {
    return __builtin_amdgcn_mfma_f32_16x16x32_bf16(a, b, c, 0, 0, 0);
}

__device__ __forceinline__ s16x8 cvt8(float4 a, float4 b) {
    union { s16x8 v; __bf16 h[8]; } u;
    u.h[0] = (__bf16)a.x; u.h[1] = (__bf16)a.y;
    u.h[2] = (__bf16)a.z; u.h[3] = (__bf16)a.w;
    u.h[4] = (__bf16)b.x; u.h[5] = (__bf16)b.y;
    u.h[6] = (__bf16)b.z; u.h[7] = (__bf16)b.w;
    return u.v;
}

// 8 waves x 16 q-rows, 32KB LDS (no P buffer), swapped-QK^T in-register softmax.
__launch_bounds__(512, 4)
__global__ void attn_kernel(const float* __restrict__ q, const float* __restrict__ k,
                            const float* __restrict__ v, const float* __restrict__ mask,
                            const float* __restrict__ mem, float* __restrict__ ctx)
{
    __shared__ __bf16 Klds[KB_ * HD_];        // 16 KB, swizzled rows
    __shared__ __bf16 Vt[HD_ * KB_];          // 16 KB, transposed + swizzled

    const int tid  = threadIdx.x;
    const int lane = tid & 63;
    const int w    = tid >> 6;                // 0..7
    const int l15  = lane & 15;
    const int l4   = lane >> 4;               // 0..3
    const int xv   = (lane & 7) << 4;

    const int qt   = blockIdx.x >> 7;
    const int pair = blockIdx.x & 127;
    const int b    = pair >> 5;
    const int h    = pair & 31;
    const int q0   = qt * QB_;

    // ---- Q fragments (B-operand; lane l15 = q-row, l4*8+j = d), scale folded ----
    const float scale = 0.088388347648318447f;   // 1/sqrt(128)
    s16x8 qf[4];
    {
        const float* qbase = q + (((size_t)(b * NH_ + h)) * SQ_ + q0 + w * 16 + l15) * HD_;
        #pragma unroll
        for (int kc = 0; kc < 4; ++kc) {
            const float* p = qbase + kc * 32 + l4 * 8;
            float4 a = *(const float4*)p;
            float4 c = *(const float4*)(p + 4);
            a.x *= scale; a.y *= scale; a.z *= scale; a.w *= scale;
            c.x *= scale; c.y *= scale; c.z *= scale; c.w *= scale;
            qf[kc] = cvt8(a, c);
        }
    }

    // O accumulator: acc[nn] rows q = l4*4+r, cols hd = nn*16 + l15
    f32x4 acc[8];
    #pragma unroll
    for (int n = 0; n < 8; ++n) acc[n] = (f32x4){0.f, 0.f, 0.f, 0.f};

    // per-lane column stats for q = w*16 + l15
    float mrun = -3.0e38f, lrun = 0.f;

    const float* maskrow = mask + ((size_t)b * SQ_ + q0 + w * 16 + l15) * KT_;

    for (int t = 0; t < NTILE_; ++t) {
        const int kv0 = t * KB_;
        const float *srcK, *srcV;
        int rstride;
        if (t < MEMTILES_) {
            const float* mrow = mem + ((size_t)b * MLEN_ + kv0) * (2 * NH_ * HD_) + h * HD_;
            srcK = mrow;
            srcV = mrow + NH_ * HD_;
            rstride = 2 * NH_ * HD_;
        } else {
            size_t off = (((size_t)b * NH_ + h) * SQ_ + (kv0 - MLEN_)) * HD_;
            srcK = k + off;
            srcV = v + off;
            rstride = HD_;
        }

        __syncthreads();   // previous tile's LDS reads complete

        // ---- K stage ----
        #pragma unroll
        for (int it = 0; it < 2; ++it) {
            int idx = tid + it * 512;
            int row = idx >> 4, cg = idx & 15;
            const float* p = srcK + (size_t)row * rstride + cg * 8;
            float4 a = *(const float4*)p;
            float4 c = *(const float4*)(p + 4);
            s16x8 vv = cvt8(a, c);
            int byte = row * 256 + ((cg * 16) ^ ((row & 7) << 4));
            *(s16x8*)((char*)Klds + byte) = vv;
        }
        // ---- V stage (transposed) ----
        #pragma unroll
        for (int it = 0; it < 2; ++it) {
            int idx = tid + it * 512;
            int hd = idx & 127, kvb = idx >> 7;
            const float* p = srcV + (size_t)(kvb * 8) * rstride + hd;
            union { s16x8 v; __bf16 hh[8]; } u;
            #pragma unroll
            for (int j = 0; j < 8; ++j) u.hh[j] = (__bf16)p[(size_t)j * rstride];
            int byte = hd * 128 + ((kvb * 16) ^ ((hd & 7) << 4));
            *(s16x8*)((char*)Vt + byte) = u.v;
        }

        __syncthreads();   // tile staged

        // ---- mask loads: lane needs mask[q=w16+l15][kv0 + mt*16 + l4*4 .. +3] ----
        f32x4 mk[4];
        #pragma unroll
        for (int mt = 0; mt < 4; ++mt)
            mk[mt] = *(const f32x4*)(maskrow + kv0 + mt * 16 + l4 * 4);

        // ---- S^T = K @ Q^T : st[mt] rows kv = mt*16 + l4*4 + r, cols q = l15 ----
        f32x4 st[4];
        #pragma unroll
        for (int mt = 0; mt < 4; ++mt) st[mt] = (f32x4){0.f, 0.f, 0.f, 0.f};
        #pragma unroll
        for (int mt = 0; mt < 4; ++mt) {
            #pragma unroll
            for (int kc = 0; kc < 4; ++kc) {
                s16x8 kf = *(const s16x8*)((const char*)Klds +
                            (mt * 16 + l15) * 256 + (((kc * 4 + l4) * 16) ^ xv));
                st[mt] = MFMA16(kf, qf[kc], st[mt]);
            }
        }

        // ---- mask apply ----
        #pragma unroll
        for (int mt = 0; mt < 4; ++mt)
            #pragma unroll
            for (int r = 0; r < 4; ++r)
                st[mt][r] = fmaf(mk[mt][r], st[mt][r] + 10000.f, -10000.f);

        // ---- in-register softmax over kv (16 in-lane + 2 shfl) ----
        float x0 = fmaxf(fmaxf(st[0][0], st[0][1]), fmaxf(st[0][2], st[0][3]));
        float x1 = fmaxf(fmaxf(st[1][0], st[1][1]), fmaxf(st[1][2], st[1][3]));
        float x2 = fmaxf(fmaxf(st[2][0], st[2][1]), fmaxf(st[2][2], st[2][3]));
        float x3 = fmaxf(fmaxf(st[3][0], st[3][1]), fmaxf(st[3][2], st[3][3]));
        float rm = fmaxf(fmaxf(x0, x1), fmaxf(x2, x3));
        rm = fmaxf(rm, __shfl_xor(rm, 16));
        rm = fmaxf(rm, __shfl_xor(rm, 32));

        if (!__all(rm <= mrun + 8.f)) {       // defer-max: rescale only on real growth
            float nm = fmaxf(mrun, rm);
            float al = __expf(mrun - nm);
            mrun = nm;
            lrun *= al;
            float alr0 = __shfl(al, l4 * 4 + 0);
            float alr1 = __shfl(al, l4 * 4 + 1);
            float alr2 = __shfl(al, l4 * 4 + 2);
            float alr3 = __shfl(al, l4 * 4 + 3);
            #pragma unroll
            for (int nn = 0; nn < 8; ++nn) {
                acc[nn][0] *= alr0; acc[nn][1] *= alr1;
                acc[nn][2] *= alr2; acc[nn][3] *= alr3;
            }
        }

        float rs = 0.f;
        #pragma unroll
        for (int mt = 0; mt < 4; ++mt) {
            #pragma unroll
            for (int r = 0; r < 4; ++r) {
                float pe = __expf(st[mt][r] - mrun);
                st[mt][r] = pe;
                rs += pe;
            }
        }
        rs += __shfl_xor(rs, 16);
        rs += __shfl_xor(rs, 32);
        lrun += rs;

        // ---- pack P^T to bf16: pk[mt] = {P[kv=mt*16+l4*4+0..3][q=l15]} ----
        union PK { int d[2]; __bf16 hh[4]; };
        PK pk0, pk1, pk2, pk3;
        pk0.hh[0]=(__bf16)st[0][0]; pk0.hh[1]=(__bf16)st[0][1]; pk0.hh[2]=(__bf16)st[0][2]; pk0.hh[3]=(__bf16)st[0][3];
        pk1.hh[0]=(__bf16)st[1][0]; pk1.hh[1]=(__bf16)st[1][1]; pk1.hh[2]=(__bf16)st[1][2]; pk1.hh[3]=(__bf16)st[1][3];
        pk2.hh[0]=(__bf16)st[2][0]; pk2.hh[1]=(__bf16)st[2][1]; pk2.hh[2]=(__bf16)st[2][2]; pk2.hh[3]=(__bf16)st[2][3];
        pk3.hh[0]=(__bf16)st[3][0]; pk3.hh[1]=(__bf16)st[3][1]; pk3.hh[2]=(__bf16)st[3][2]; pk3.hh[3]=(__bf16)st[3][3];

        // ---- assemble PV A-fragments: pa[kt] lane needs P[q=l15][kv=kt*32+l4*8+j] ----
        const int srcA = (l4 & 1) * 32 + l15;   // holder of j=0..3 (its r=0..3)
        const int srcB = srcA + 16;             // holder of j=4..7
        const int sel  = l4 >> 1;               // which mt' = kt*2 + sel
        s16x8 pa[2];
        {
            union { int d[4]; s16x8 v; } ua;
            int a00 = __shfl(pk0.d[0], srcA), a10 = __shfl(pk1.d[0], srcA);
            int a01 = __shfl(pk0.d[1], srcA), a11 = __shfl(pk1.d[1], srcA);
            int b00 = __shfl(pk0.d[0], srcB), b10 = __shfl(pk1.d[0], srcB);
            int b01 = __shfl(pk0.d[1], srcB), b11 = __shfl(pk1.d[1], srcB);
            ua.d[0] = sel ? a10 : a00; ua.d[1] = sel ? a11 : a01;
            ua.d[2] = sel ? b10 : b00; ua.d[3] = sel ? b11 : b01;
            pa[0] = ua.v;
        }
        {
            union { int d[4]; s16x8 v; } ua;
            int a00 = __shfl(pk2.d[0], srcA), a10 = __shfl(pk3.d[0], srcA);
            int a01 = __shfl(pk2.d[1], srcA), a11 = __shfl(pk3.d[1], srcA);
            int b00 = __shfl(pk2.d[0], srcB), b10 = __shfl(pk3.d[0], srcB);
            int b01 = __shfl(pk2.d[1], srcB), b11 = __shfl(pk3.d[1], srcB);
            ua.d[0] = sel ? a10 : a00; ua.d[1] = sel ? a11 : a01;
            ua.d[2] = sel ? b10 : b00; ua.d[3] = sel ? b11 : b01;
            pa[1] = ua.v;
        }

        // ---- O += P @ V ----
        #pragma unroll
        for (int nn = 0; nn < 8; ++nn) {
            s16x8 vf0 = *(const s16x8*)((const char*)Vt +
                          (nn * 16 + l15) * 128 + ((l4 * 16) ^ xv));
            s16x8 vf1 = *(const s16x8*)((const char*)Vt +
                          (nn * 16 + l15) * 128 + ((64 + l4 * 16) ^ xv));
            acc[nn] = MFMA16(pa[0], vf0, acc[nn]);
            acc[nn] = MFMA16(pa[1], vf1, acc[nn]);
        }
    }

    // ---- epilogue: rows q = l4*4+r need lrun held at lane l15 = l4*4+r ----
    float lr0 = __shfl(lrun, l4 * 4 + 0);
    float lr1 = __shfl(lrun, l4 * 4 + 1);
    float lr2 = __shfl(lrun, l4 * 4 + 2);
    float lr3 = __shfl(lrun, l4 * 4 + 3);
    float inv0 = 1.f / lr0, inv1 = 1.f / lr1, inv2 = 1.f / lr2, inv3 = 1.f / lr3;
    float* obase = ctx + (((size_t)(b * NH_ + h)) * SQ_ + q0 + w * 16 + l4 * 4) * HD_ + l15;
    #pragma unroll
    for (int nn = 0; nn < 8; ++nn) {
        obase[(size_t)0 * HD_ + nn * 16] = acc[nn][0] * inv0;
        obase[(size_t)1 * HD_ + nn * 16] = acc[nn][1] * inv1;
        obase[(size_t)2 * HD_ + nn * 16] = acc[nn][2] * inv2;
        obase[(size_t)3 * HD_ + nn * 16] = acc[nn][3] * inv3;
    }
}

// cache_kv: out[b][s][part][h][d] = (part ? v : k)[b][h][s][d]
__global__ void cachekv_kernel(const float* __restrict__ k, const float* __restrict__ v,
                               float* __restrict__ out)
{
    size_t i = ((size_t)blockIdx.x * 256 + threadIdx.x) * 4;
    unsigned f = (unsigned)i;
    unsigned d    = f & 127;
    unsigned hh   = (f >> 7) & 31;
    unsigned part = (f >> 12) & 1;
    unsigned s    = (f >> 13) & 511;
    unsigned bb   = f >> 22;
    const float* src = (part ? v : k) + (((size_t)(bb * 32u + hh)) * 512u + s) * 128u + d;
    *(float4*)(out + i) = *(const float4*)src;
}

extern "C" void kernel_launch(void* const* d_in, const int* in_sizes, int n_in,
                              void* d_out, int out_size, void* d_ws, size_t ws_size,
                              hipStream_t stream) {
    const float* q    = (const float*)d_in[0];
    const float* k    = (const float*)d_in[1];
    const float* v    = (const float*)d_in[2];
    const float* mask = (const float*)d_in[3];
    const float* mem  = (const float*)d_in[4];
    float* out = (float*)d_out;

    attn_kernel<<<dim3(B_ * NH_ * (SQ_ / QB_)), dim3(512), 0, stream>>>(q, k, v, mask, mem, out);

    const int ctx_elems = B_ * NH_ * SQ_ * HD_;                 // 8388608
    const int ckv_elems = B_ * SQ_ * 2 * NH_ * HD_;             // 16777216
    cachekv_kernel<<<dim3(ckv_elems / 4 / 256), dim3(256), 0, stream>>>(k, v, out + ctx_elems);
    (void)in_sizes; (void)n_in; (void)out_size; (void)d_ws; (void)ws_size;
}